// Round 14
// baseline (193.921 us; speedup 1.0000x reference)
//
#include <hip/hip_runtime.h>
#include <stdint.h>

#define DIM   1024
#define L_SEQ 2048
#define BATCH 2
#define NH    8
#define M_TOT 4096   // BATCH * L_SEQ
#define EPS_F 1e-5f

typedef __bf16 bf16x8 __attribute__((ext_vector_type(8)));
typedef unsigned short u16x8 __attribute__((ext_vector_type(8)));
typedef float f32x4 __attribute__((ext_vector_type(4)));

__device__ __forceinline__ unsigned short f2bf(float f) {
  unsigned int u = __float_as_uint(f);
  u += 0x7FFFu + ((u >> 16) & 1u);   // RNE
  return (unsigned short)(u >> 16);
}

__device__ __forceinline__ f32x4 mfma_bf16(u16x8 a, u16x8 b, f32x4 c) {
  return __builtin_amdgcn_mfma_f32_16x16x32_bf16(
      __builtin_bit_cast(bf16x8, a), __builtin_bit_cast(bf16x8, b), c, 0, 0, 0);
}

__device__ __forceinline__ float silu_f(float v) {
  return v / (1.f + __expf(-v));
}

// async global -> LDS, 16 bytes per lane (global_load_lds_dwordx4)
__device__ __forceinline__ void gload16(const unsigned short* g, unsigned short* l) {
  __builtin_amdgcn_global_load_lds(
      (const __attribute__((address_space(1))) unsigned int*)g,
      (__attribute__((address_space(3))) unsigned int*)l, 16, 0, 0);
}

// ---- prep: blocks 0..4095 -> dt + x->bf16 (register-resident dot); 4096.. -> weight cvt ----
__global__ __launch_bounds__(256) void prep_kernel(const float* __restrict__ x,
                                                   const float* __restrict__ W_dt,
                                                   const float* __restrict__ b_dt,
                                                   const float* __restrict__ ln_a,
                                                   const float4* __restrict__ wz,
                                                   const float4* __restrict__ wza,
                                                   const float4* __restrict__ wya,
                                                   float* __restrict__ ln_da,
                                                   unsigned short* __restrict__ xb,
                                                   ushort4* __restrict__ wzb,
                                                   ushort4* __restrict__ wzab,
                                                   ushort4* __restrict__ wyab,
                                                   float* __restrict__ Zs) {
  const int blk = blockIdx.x;
  const int tid = threadIdx.x;
  if (blk >= 4096) {
    const int wb = blk - 4096;
    if (wb < 2) ((f32x4*)Zs)[wb * 256 + tid] = f32x4{0.f, 0.f, 0.f, 0.f};
    int i = wb * 256 + tid;                    // 0 .. 786431
    const float4* s; ushort4* d; int j;
    if (i < 262144)      { s = wz;  d = wzb;  j = i; }
    else if (i < 524288) { s = wza; d = wzab; j = i - 262144; }
    else                 { s = wya; d = wyab; j = i - 524288; }
    float4 f = s[j];
    d[j] = make_ushort4(f2bf(f.x), f2bf(f.y), f2bf(f.z), f2bf(f.w));
    return;
  }
  // dt + x->bf16: each thread keeps its 4 x-elements in registers; no xs LDS.
  __shared__ float partials[NH][4];
  const int row = blk;                         // 0..4095
  const int wave = tid >> 6, lane = tid & 63;
  float4 f = ((const float4*)(x + (size_t)row * DIM))[tid];
  ((ushort4*)(xb + (size_t)row * DIM))[tid] =
      make_ushort4(f2bf(f.x), f2bf(f.y), f2bf(f.z), f2bf(f.w));
#pragma unroll
  for (int h = 0; h < NH; ++h) {
    const float4 w = ((const float4*)(W_dt + (size_t)h * DIM))[tid];
    float p = f.x * w.x + f.y * w.y + f.z * w.z + f.w * w.w;
    for (int off = 32; off > 0; off >>= 1) p += __shfl_down(p, off);
    if (lane == 0) partials[h][wave] = p;
  }
  __syncthreads();
  if (tid < 32) {
    const int h = tid >> 2, wv = tid & 3;
    float s = partials[h][wv];
    s += __shfl_down(s, 1);
    s += __shfl_down(s, 2);
    if (wv == 0) {
      float t = s + b_dt[h];
      float sp = (t > 20.f) ? t : log1pf(expf(t));
      int b = row >> 11, l = row & (L_SEQ - 1);
      ln_da[(size_t)(b * NH + h) * L_SEQ + l] = -expf(ln_a[h]) * sp;
    }
  }
}

// ---- merged GEMM, 1024 blocks = exactly 4/CU, uniform N64 tiles, XCD-clustered:
//   sel<2 : z-block, M128 x N64, DUAL GEMM (Wz + Wza) -> colsum/wdiag epilogue (32 MFMA/kt)
//   sel>=2: y-block, M128 x N64, single GEMM (Wya)    -> Sy = silu(C+b) into d_out (16 MFMA/kt)
// Mapping: xcd = flat&7 (n-tile clustering per XCD), mt = (flat>>3)&31, sel = flat>>8.
// sel in dispatch-slot order => each CU hosts ~2 z + 2 y: per-CU per-kt work uniform.
// 2-barrier K-loop is the verified source-level plateau (R8/R12, learn_hip m99-m141).
__global__ __launch_bounds__(256, 4) void gemm_all(const unsigned short* __restrict__ xb,
                                                   const unsigned short* __restrict__ Wz,
                                                   const unsigned short* __restrict__ Wza,
                                                   const unsigned short* __restrict__ Wya,
                                                   const float* __restrict__ b_z,
                                                   const float* __restrict__ b_za,
                                                   const float* __restrict__ b_ya,
                                                   float* __restrict__ Zs,
                                                   float* __restrict__ wdiag,
                                                   float* __restrict__ Sy) {
  __shared__ __align__(16) unsigned short As[128 * 64];   // 16 KB
  __shared__ __align__(16) unsigned short Bs[128 * 64];   // 16 KB (y uses lower 8 KB)
  __shared__ float colsum[64];

  const int tid = threadIdx.x;
  const int lane = tid & 63, wave = tid >> 6;
  const int wm = wave >> 1, wn = wave & 1;
  const int l16 = lane & 15, quad = lane >> 4;

  const int flat = blockIdx.x;
  const int xcd = flat & 7;
  const int mt = (flat >> 3) & 31;
  const int sel = flat >> 8;                   // 0..3
  const bool isZ = (sel < 2);
  const int n0 = isZ ? (2 * xcd + sel) * 64 : (2 * xcd + sel - 2) * 64;
  const int m0 = mt * 128;

  // lean per-lane staging offsets (elements)
  const int rowl = tid >> 3;                   // 0..31
  const int g = (tid & 7) ^ (rowl & 7);        // XOR-swizzled k-chunk
  const size_t aoff = (size_t)(m0 + rowl) * DIM + g * 8;
  const size_t boff = (size_t)(n0 + rowl) * DIM + g * 8;
  const unsigned short* bp0 = isZ ? Wz : Wya;  // slots 0,1 (rows 0..63 of the N64 tile)
  const unsigned short* bp1 = Wza;             // z only: slots 2,3
  unsigned short* AsD = As + tid * 8;
  unsigned short* BsD = Bs + tid * 8;

  f32x4 acc[4][4];
  const f32x4 zero = {0.f, 0.f, 0.f, 0.f};
  for (int i = 0; i < 4; ++i)
    for (int jj = 0; jj < 4; ++jj) acc[i][jj] = zero;

  for (int kt = 0; kt < 16; ++kt) {
    const size_t k0 = (size_t)kt * 64;
    __syncthreads();
    gload16(xb  + aoff + k0,                AsD);
    gload16(xb  + aoff + 32 * DIM + k0,     AsD + 2048);
    gload16(xb  + aoff + 64 * DIM + k0,     AsD + 4096);
    gload16(xb  + aoff + 96 * DIM + k0,     AsD + 6144);
    gload16(bp0 + boff + k0,                BsD);
    gload16(bp0 + boff + 32 * DIM + k0,     BsD + 2048);
    if (isZ) {
      gload16(bp1 + boff + k0,              BsD + 4096);
      gload16(bp1 + boff + 32 * DIM + k0,   BsD + 6144);
    }
    __syncthreads();   // drains vmcnt(0): staged data visible
#pragma unroll
    for (int kk = 0; kk < 2; ++kk) {
      const int kc = kk * 4 + quad;
      u16x8 aF[4];
#pragma unroll
      for (int rb = 0; rb < 4; ++rb) {
        const int r = wm * 64 + rb * 16 + l16;
        aF[rb] = *(const u16x8*)&As[r * 64 + ((kc ^ (r & 7)) << 3)];
      }
      if (isZ) {
        u16x8 bF[4];
#pragma unroll
        for (int cb = 0; cb < 4; ++cb) {
          const int r = (cb < 2) ? (wn * 32 + cb * 16 + l16)
                                 : (64 + wn * 32 + (cb - 2) * 16 + l16);
          bF[cb] = *(const u16x8*)&Bs[r * 64 + ((kc ^ (r & 7)) << 3)];
        }
#pragma unroll
        for (int rb = 0; rb < 4; ++rb)
#pragma unroll
          for (int cb = 0; cb < 4; ++cb)
            acc[rb][cb] = mfma_bf16(aF[rb], bF[cb], acc[rb][cb]);
      } else {
        u16x8 bF[2];
#pragma unroll
        for (int cb = 0; cb < 2; ++cb) {
          const int r = wn * 32 + cb * 16 + l16;
          bF[cb] = *(const u16x8*)&Bs[r * 64 + ((kc ^ (r & 7)) << 3)];
        }
#pragma unroll
        for (int rb = 0; rb < 4; ++rb)
#pragma unroll
          for (int cb = 0; cb < 2; ++cb)
            acc[rb][cb] = mfma_bf16(aF[rb], bF[cb], acc[rb][cb]);
      }
    }
  }

  if (isZ) {
    // U = acc[.][cb] (cb<2) + b_z, V = acc[.][cb+2] + b_za
    __syncthreads();
    if (tid < 64) colsum[tid] = 0.f;
    __syncthreads();
    const int b = m0 >> 11;
#pragma unroll
    for (int cb = 0; cb < 2; ++cb) {
      const int nl = wn * 32 + cb * 16 + l16;       // 0..63
      const int n = n0 + nl;
      const int h = n >> 7;
      const float bz = b_z[n], ba = b_za[n];
      float ssum = 0.f;
#pragma unroll
      for (int rb = 0; rb < 4; ++rb) {
        const int mlb = wm * 64 + rb * 16 + quad * 4;
#pragma unroll
        for (int r = 0; r < 4; ++r) {
          const int l = (m0 + mlb + r) & (L_SEQ - 1);
          float u  = acc[rb][cb][r] + bz;
          float vv = acc[rb][cb + 2][r] + ba;
          if (l > h) ssum += u * silu_f(vv);
          else if (l == h)
            wdiag[(size_t)(b * NH + h) * 128 + (n & 127)] = u * silu_f(vv);
        }
      }
      atomicAdd(&colsum[nl], ssum);
    }
    __syncthreads();
    if (tid < 64) atomicAdd(&Zs[(size_t)b * DIM + n0 + tid], colsum[tid]);
  } else {
#pragma unroll
    for (int cb = 0; cb < 2; ++cb) {
      const int nl = wn * 32 + cb * 16 + l16;       // 0..63
      const float bb = b_ya[n0 + nl];
#pragma unroll
      for (int rb = 0; rb < 4; ++rb) {
        const int mlb = wm * 64 + rb * 16 + quad * 4;
#pragma unroll
        for (int r = 0; r < 4; ++r)
          Sy[(size_t)(m0 + mlb + r) * DIM + n0 + nl] = silu_f(acc[rb][cb][r] + bb);
      }
    }
  }
}

// ---- per (b,h): stats on wave 0, then 4-wave parallel scan (8 chunks/wave) ----
__global__ __launch_bounds__(256) void stats_scan(const float* __restrict__ Zs,
                                                  const float* __restrict__ hidden,
                                                  const float* __restrict__ wdiag,
                                                  const float* __restrict__ gn_w,
                                                  const float* __restrict__ ln_da,
                                                  float* __restrict__ vtg,
                                                  float* __restrict__ wtg,
                                                  float* __restrict__ alpha2,
                                                  float* __restrict__ hidden_next) {
  const int bh = blockIdx.x, b = bh >> 3, h = bh & 7;
  const int tid = threadIdx.x, wv = tid >> 6, lane = tid & 63;
  __shared__ float csumS[32];
  __shared__ float statS[4];   // svv, svw, sww, total

  float v0 = 0.f, v1 = 0.f, w0 = 0.f, w1 = 0.f;
  const size_t base = (size_t)bh * 128;
  if (wv == 0) {
    v0 = Zs[(size_t)b * DIM + h * 128 + lane]      + hidden[base + lane];
    v1 = Zs[(size_t)b * DIM + h * 128 + 64 + lane] + hidden[base + 64 + lane];
    w0 = wdiag[base + lane];
    w1 = wdiag[base + 64 + lane];
    float sv = v0 + v1, sw = w0 + w1;
    for (int off = 32; off > 0; off >>= 1) {
      sv += __shfl_down(sv, off);
      sw += __shfl_down(sw, off);
    }
    const float muv = __shfl(sv, 0) * (1.f / 128.f);
    const float muw = __shfl(sw, 0) * (1.f / 128.f);
    const float a0 = v0 - muv, a1 = v1 - muv;
    const float c0 = w0 - muw, c1 = w1 - muw;
    float rvv = a0 * a0 + a1 * a1;
    float rvw = a0 * c0 + a1 * c1;
    float rww = c0 * c0 + c1 * c1;
    for (int off = 32; off > 0; off >>= 1) {
      rvv += __shfl_down(rvv, off);
      rvw += __shfl_down(rvw, off);
      rww += __shfl_down(rww, off);
    }
    if (lane == 0) {
      statS[0] = rvv * (1.f / 128.f);
      statS[1] = rvw * (1.f / 128.f);
      statS[2] = rww * (1.f / 128.f);
    }
    const float gw = gn_w[h];
    vtg[base + lane] = a0 * gw;  vtg[base + 64 + lane] = a1 * gw;
    wtg[base + lane] = c0 * gw;  wtg[base + 64 + lane] = c1 * gw;
  }

  // phase 1: per-wave intra-chunk inclusive prefix on 8 chunks
  const float* src = ln_da + (size_t)bh * L_SEQ;
  float vals[8];
#pragma unroll
  for (int jj = 0; jj < 8; ++jj) {
    const int c = wv * 8 + jj;
    float val = src[c * 64 + lane];
#pragma unroll
    for (int off = 1; off < 64; off <<= 1) {
      float nv = __shfl_up(val, off);
      if (lane >= off) val += nv;
    }
    vals[jj] = val;
    if (lane == 63) csumS[c] = val;
  }
  __syncthreads();

  // phase 2: wave 0 lanes 0..31: exclusive scan of the 32 chunk totals
  if (tid < 32) {
    float s = csumS[tid];
    float incl = s;
#pragma unroll
    for (int off = 1; off < 32; off <<= 1) {
      float nv = __shfl_up(incl, off);
      if (tid >= off) incl += nv;
    }
    csumS[tid] = incl - s;            // exclusive carry
    if (tid == 31) statS[3] = incl;   // grand total
  }
  __syncthreads();

  // phase 3: apply carries, compute alpha2
  const float svv = statS[0], svw = statS[1], sww = statS[2];
#pragma unroll
  for (int jj = 0; jj < 8; ++jj) {
    const int c = wv * 8 + jj;
    const float S = csumS[c] + vals[jj];
    const float ce = expf(S);
    const float D = rsqrtf(ce * ce * svv + 2.f * ce * svw + sww + EPS_F);
    const int l = c * 64 + lane;
    float* ap = alpha2 + ((size_t)(b * L_SEQ + l) * NH + h) * 2;
    ap[0] = ce * D;
    ap[1] = D;
  }
  if (wv == 0) {
    const float clast = expf(statS[3]);
    hidden_next[base + lane]      = clast * v0 + w0;
    hidden_next[base + 64 + lane] = clast * v1 + w1;
  }
}

// ---- per row n of W_y: Gv[bh][n], Gw[bh][n] (all 16 bh) and constc[n] ----
__global__ __launch_bounds__(256) void proj_kernel(const float* __restrict__ W_y,
                                                   const float* __restrict__ vtg,
                                                   const float* __restrict__ wtg,
                                                   const float* __restrict__ gn_b,
                                                   const float* __restrict__ b_y,
                                                   float* __restrict__ Gv,
                                                   float* __restrict__ Gw,
                                                   float* __restrict__ constc) {
  const int tid = threadIdx.x, wave = tid >> 6, lane = tid & 63;
  const int n = blockIdx.x * 4 + wave;
  const float4* row = (const float4*)(W_y + (size_t)n * DIM);
  const int half = lane >> 5, l32 = lane & 31;
  float cc = 0.f;
#pragma unroll
  for (int p = 0; p < 4; ++p) {
    const int h = p * 2 + half;
    float4 wv = row[p * 64 + lane];
    const float4 va = *(const float4*)&vtg[(size_t)h * 128 + l32 * 4];
    const float4 vb = *(const float4*)&vtg[(size_t)(8 + h) * 128 + l32 * 4];
    const float4 wa = *(const float4*)&wtg[(size_t)h * 128 + l32 * 4];
    const float4 wb = *(const float4*)&wtg[(size_t)(8 + h) * 128 + l32 * 4];
    float gv0 = wv.x * va.x + wv.y * va.y + wv.z * va.z + wv.w * va.w;
    float gv1 = wv.x * vb.x + wv.y * vb.y + wv.z * vb.z + wv.w * vb.w;
    float gw0 = wv.x * wa.x + wv.y * wa.y + wv.z * wa.z + wv.w * wa.w;
    float gw1 = wv.x * wb.x + wv.y * wb.y + wv.z * wb.z + wv.w * wb.w;
    cc += (wv.x + wv.y + wv.z + wv.w) * gn_b[h];
#pragma unroll
    for (int off = 16; off > 0; off >>= 1) {
      gv0 += __shfl_down(gv0, off, 32);
      gv1 += __shfl_down(gv1, off, 32);
      gw0 += __shfl_down(gw0, off, 32);
      gw1 += __shfl_down(gw1, off, 32);
    }
    if (l32 == 0) {
      Gv[(size_t)h * DIM + n]       = gv0;
      Gv[(size_t)(8 + h) * DIM + n] = gv1;
      Gw[(size_t)h * DIM + n]       = gw0;
      Gw[(size_t)(8 + h) * DIM + n] = gw1;
    }
  }
  for (int off = 32; off > 0; off >>= 1) cc += __shfl_down(cc, off);
  if (lane == 0) constc[n] = b_y[n] + cc;
}

// ---- finalize: y[m,n] = (constc[n] + sum_k alpha2[m,k]*G[k,n]) * Sy[m,n], in place ----
__global__ __launch_bounds__(256) void finalize(const float* __restrict__ alpha2,
                                                const float* __restrict__ Gv,
                                                const float* __restrict__ Gw,
                                                const float* __restrict__ constc,
                                                float* __restrict__ y) {
  const int tid = threadIdx.x;
  const int n0 = blockIdx.x * 256;
  const int m0 = blockIdx.y * 64;
  const int b = m0 >> 11;
  __shared__ float aS[64 * 16];
  ((float4*)aS)[tid] = ((const float4*)(alpha2 + (size_t)m0 * 16))[tid];
  __syncthreads();
  const int c = tid & 63;     // col4 within n-tile
  const int rg = tid >> 6;    // row group (16 rows each)
  const int n = n0 + c * 4;
  f32x4 g[16 * 2];
#pragma unroll
  for (int h = 0; h < 8; ++h) {
    g[2 * h]     = *(const f32x4*)&Gv[(size_t)(b * NH + h) * DIM + n];
    g[2 * h + 1] = *(const f32x4*)&Gw[(size_t)(b * NH + h) * DIM + n];
  }
  const f32x4 cc = *(const f32x4*)&constc[n];
#pragma unroll
  for (int jj = 0; jj < 16; ++jj) {
    const int m = m0 + rg * 16 + jj;
    const float* a = &aS[(rg * 16 + jj) * 16];
    f32x4 Ay = cc;
#pragma unroll
    for (int k = 0; k < 16; ++k) Ay += a[k] * g[k];
    f32x4 s = *(const f32x4*)&y[(size_t)m * DIM + n];
    *(f32x4*)&y[(size_t)m * DIM + n] = Ay * s;
  }
}

extern "C" void kernel_launch(void* const* d_in, const int* in_sizes, int n_in,
                              void* d_out, int out_size, void* d_ws, size_t ws_size,
                              hipStream_t stream) {
  const float* x      = (const float*)d_in[0];
  const float* hidden = (const float*)d_in[1];
  const float* W_z    = (const float*)d_in[2];
  const float* b_z    = (const float*)d_in[3];
  const float* W_za   = (const float*)d_in[4];
  const float* b_za   = (const float*)d_in[5];
  const float* W_y    = (const float*)d_in[6];
  const float* b_y    = (const float*)d_in[7];
  const float* W_ya   = (const float*)d_in[8];
  const float* b_ya   = (const float*)d_in[9];
  const float* W_dt   = (const float*)d_in[10];
  const float* b_dt   = (const float*)d_in[11];
  const float* ln_a   = (const float*)d_in[12];
  const float* gn_w   = (const float*)d_in[13];
  const float* gn_b   = (const float*)d_in[14];

  char* ws = (char*)d_ws;
  unsigned short* xb   = (unsigned short*)(ws);             // 8,388,608 B
  unsigned short* Wzb  = (unsigned short*)(ws + 8388608);   // 2,097,152 B
  unsigned short* Wzab = (unsigned short*)(ws + 10485760);  // 2,097,152 B
  unsigned short* Wyab = (unsigned short*)(ws + 12582912);  // 2,097,152 B
  float* ln_da  = (float*)(ws + 14680064);                  // 131,072 B
  float* Zs     = (float*)(ws + 14811136);                  // 8,192 B
  float* wdiag  = (float*)(ws + 14819328);                  // 8,192 B
  float* vtg    = (float*)(ws + 14827520);                  // 8,192 B
  float* wtg    = (float*)(ws + 14835712);                  // 8,192 B
  float* Gv     = (float*)(ws + 14843904);                  // 65,536 B
  float* Gw     = (float*)(ws + 14909440);                  // 65,536 B
  float* constc = (float*)(ws + 14974976);                  // 4,096 B
  float* alpha2 = (float*)(ws + 14979072);                  // 262,144 B

  float* y = (float*)d_out;
  float* hidden_next = y + (size_t)M_TOT * DIM;

  prep_kernel<<<7168, 256, 0, stream>>>(x, W_dt, b_dt, ln_a,
                                        (const float4*)W_z, (const float4*)W_za,
                                        (const float4*)W_ya,
                                        ln_da, xb, (ushort4*)Wzb, (ushort4*)Wzab,
                                        (ushort4*)Wyab, Zs);

  gemm_all<<<1024, 256, 0, stream>>>(xb, Wzb, Wzab, Wyab,
                                     b_z, b_za, b_ya, Zs, wdiag, y);

  stats_scan<<<16, 256, 0, stream>>>(Zs, hidden, wdiag, gn_w, ln_da,
                                     vtg, wtg, alpha2, hidden_next);
  proj_kernel<<<256, 256, 0, stream>>>(W_y, vtg, wtg, gn_b, b_y, Gv, Gw, constc);

  finalize<<<dim3(4, 64), 256, 0, stream>>>(alpha2, Gv, Gw, constc, y);
}

// Round 15
// 164.023 us; speedup vs baseline: 1.1823x; 1.1823x over previous
//
#include <hip/hip_runtime.h>
#include <stdint.h>

#define DIM   1024
#define L_SEQ 2048
#define BATCH 2
#define NH    8
#define M_TOT 4096   // BATCH * L_SEQ
#define EPS_F 1e-5f

typedef __bf16 bf16x8 __attribute__((ext_vector_type(8)));
typedef unsigned short u16x8 __attribute__((ext_vector_type(8)));
typedef float f32x4 __attribute__((ext_vector_type(4)));

__device__ __forceinline__ unsigned short f2bf(float f) {
  unsigned int u = __float_as_uint(f);
  u += 0x7FFFu + ((u >> 16) & 1u);   // RNE
  return (unsigned short)(u >> 16);
}

__device__ __forceinline__ f32x4 mfma_bf16(u16x8 a, u16x8 b, f32x4 c) {
  return __builtin_amdgcn_mfma_f32_16x16x32_bf16(
      __builtin_bit_cast(bf16x8, a), __builtin_bit_cast(bf16x8, b), c, 0, 0, 0);
}

__device__ __forceinline__ float silu_f(float v) {
  return v / (1.f + __expf(-v));
}

// async global -> LDS, 16 bytes per lane (global_load_lds_dwordx4)
__device__ __forceinline__ void gload16(const unsigned short* g, unsigned short* l) {
  __builtin_amdgcn_global_load_lds(
      (const __attribute__((address_space(1))) unsigned int*)g,
      (__attribute__((address_space(3))) unsigned int*)l, 16, 0, 0);
}

// ---- prep: blocks 0..4095 -> dt + x->bf16 (register-resident dot); 4096.. -> weight cvt ----
__global__ __launch_bounds__(256) void prep_kernel(const float* __restrict__ x,
                                                   const float* __restrict__ W_dt,
                                                   const float* __restrict__ b_dt,
                                                   const float* __restrict__ ln_a,
                                                   const float4* __restrict__ wz,
                                                   const float4* __restrict__ wza,
                                                   const float4* __restrict__ wya,
                                                   float* __restrict__ ln_da,
                                                   unsigned short* __restrict__ xb,
                                                   ushort4* __restrict__ wzb,
                                                   ushort4* __restrict__ wzab,
                                                   ushort4* __restrict__ wyab,
                                                   float* __restrict__ Zs) {
  const int blk = blockIdx.x;
  const int tid = threadIdx.x;
  if (blk >= 4096) {
    const int wb = blk - 4096;
    if (wb < 2) ((f32x4*)Zs)[wb * 256 + tid] = f32x4{0.f, 0.f, 0.f, 0.f};
    int i = wb * 256 + tid;                    // 0 .. 786431
    const float4* s; ushort4* d; int j;
    if (i < 262144)      { s = wz;  d = wzb;  j = i; }
    else if (i < 524288) { s = wza; d = wzab; j = i - 262144; }
    else                 { s = wya; d = wyab; j = i - 524288; }
    float4 f = s[j];
    d[j] = make_ushort4(f2bf(f.x), f2bf(f.y), f2bf(f.z), f2bf(f.w));
    return;
  }
  // dt + x->bf16: each thread keeps its 4 x-elements in registers; no xs LDS.
  __shared__ float partials[NH][4];
  const int row = blk;                         // 0..4095
  const int wave = tid >> 6, lane = tid & 63;
  float4 f = ((const float4*)(x + (size_t)row * DIM))[tid];
  ((ushort4*)(xb + (size_t)row * DIM))[tid] =
      make_ushort4(f2bf(f.x), f2bf(f.y), f2bf(f.z), f2bf(f.w));
#pragma unroll
  for (int h = 0; h < NH; ++h) {
    const float4 w = ((const float4*)(W_dt + (size_t)h * DIM))[tid];
    float p = f.x * w.x + f.y * w.y + f.z * w.z + f.w * w.w;
    for (int off = 32; off > 0; off >>= 1) p += __shfl_down(p, off);
    if (lane == 0) partials[h][wave] = p;
  }
  __syncthreads();
  if (tid < 32) {
    const int h = tid >> 2, wv = tid & 3;
    float s = partials[h][wv];
    s += __shfl_down(s, 1);
    s += __shfl_down(s, 2);
    if (wv == 0) {
      float t = s + b_dt[h];
      float sp = (t > 20.f) ? t : log1pf(expf(t));
      int b = row >> 11, l = row & (L_SEQ - 1);
      ln_da[(size_t)(b * NH + h) * L_SEQ + l] = -expf(ln_a[h]) * sp;
    }
  }
}

// ---- merged GEMM, balanced blocks, single-buffer BK=64, lean addressing, XCD-clustered:
//   nt<16 : z-block, M128 x N64, DUAL GEMM (Wz + Wza)  -> colsum/wdiag epilogue
//   nt>=16: y-block, M128 x N128, single GEMM (Wya)    -> Sy = silu(C+b) into d_out
// 1D grid of 768 (3 blocks/CU); flat -> (nt,mt) clusters 3 n-tiles per XCD (B L2-resident).
// This configuration is the empirical optimum: dbuf (R8), split (R10), A-direct (R12),
// and 4-blocks/CU N64-uniform (R14) all regressed or were neutral. 2-barrier K-loop is
// the verified source-level plateau (learn_hip m99-m141).
__global__ __launch_bounds__(256, 4) void gemm_all(const unsigned short* __restrict__ xb,
                                                   const unsigned short* __restrict__ Wz,
                                                   const unsigned short* __restrict__ Wza,
                                                   const unsigned short* __restrict__ Wya,
                                                   const float* __restrict__ b_z,
                                                   const float* __restrict__ b_za,
                                                   const float* __restrict__ b_ya,
                                                   float* __restrict__ Zs,
                                                   float* __restrict__ wdiag,
                                                   float* __restrict__ Sy) {
  __shared__ __align__(16) unsigned short As[128 * 64];   // 16 KB
  __shared__ __align__(16) unsigned short Bs[128 * 64];   // 16 KB
  __shared__ float colsum[64];

  const int tid = threadIdx.x;
  const int lane = tid & 63, wave = tid >> 6;
  const int wm = wave >> 1, wn = wave & 1;
  const int l16 = lane & 15, quad = lane >> 4;

  const int flat = blockIdx.x;
  const int xcd = flat & 7;
  const int j = flat >> 3;
  const int nt = 3 * xcd + (j % 3);            // 0..23, 3 per XCD
  const int mt = j / 3;                        // 0..31
  const bool isZ = (nt < 16);
  const int n0 = isZ ? nt * 64 : (nt - 16) * 128;
  const int m0 = mt * 128;

  // lean per-lane staging offsets (elements)
  const int rowl = tid >> 3;                   // 0..31
  const int g = (tid & 7) ^ (rowl & 7);        // XOR-swizzled k-chunk
  const size_t aoff = (size_t)(m0 + rowl) * DIM + g * 8;
  const size_t boff = (size_t)(n0 + rowl) * DIM + g * 8;
  const unsigned short* bp0 = isZ ? Wz : Wya;                        // slots 0,1
  const unsigned short* bp1 = isZ ? Wza : (Wya + (size_t)64 * DIM);  // slots 2,3
  unsigned short* AsD = As + tid * 8;
  unsigned short* BsD = Bs + tid * 8;

  f32x4 acc[4][4];
  const f32x4 zero = {0.f, 0.f, 0.f, 0.f};
  for (int i = 0; i < 4; ++i)
    for (int jj = 0; jj < 4; ++jj) acc[i][jj] = zero;

  for (int kt = 0; kt < 16; ++kt) {
    const size_t k0 = (size_t)kt * 64;
    __syncthreads();
    gload16(xb  + aoff + k0,                AsD);
    gload16(xb  + aoff + 32 * DIM + k0,     AsD + 2048);
    gload16(xb  + aoff + 64 * DIM + k0,     AsD + 4096);
    gload16(xb  + aoff + 96 * DIM + k0,     AsD + 6144);
    gload16(bp0 + boff + k0,                BsD);
    gload16(bp0 + boff + 32 * DIM + k0,     BsD + 2048);
    gload16(bp1 + boff + k0,                BsD + 4096);
    gload16(bp1 + boff + 32 * DIM + k0,     BsD + 6144);
    __syncthreads();   // drains vmcnt(0): staged data visible
#pragma unroll
    for (int kk = 0; kk < 2; ++kk) {
      const int kc = kk * 4 + quad;
      u16x8 aF[4], bF[4];
#pragma unroll
      for (int rb = 0; rb < 4; ++rb) {
        const int r = wm * 64 + rb * 16 + l16;
        aF[rb] = *(const u16x8*)&As[r * 64 + ((kc ^ (r & 7)) << 3)];
      }
#pragma unroll
      for (int cb = 0; cb < 4; ++cb) {
        int r;
        if (isZ) r = (cb < 2) ? (wn * 32 + cb * 16 + l16)
                              : (64 + wn * 32 + (cb - 2) * 16 + l16);
        else     r = wn * 64 + cb * 16 + l16;
        bF[cb] = *(const u16x8*)&Bs[r * 64 + ((kc ^ (r & 7)) << 3)];
      }
#pragma unroll
      for (int rb = 0; rb < 4; ++rb)
#pragma unroll
        for (int cb = 0; cb < 4; ++cb)
          acc[rb][cb] = mfma_bf16(aF[rb], bF[cb], acc[rb][cb]);
    }
  }

  if (isZ) {
    // U = acc[.][cb] (cb<2) + b_z, V = acc[.][cb+2] + b_za
    __syncthreads();
    if (tid < 64) colsum[tid] = 0.f;
    __syncthreads();
    const int b = m0 >> 11;
#pragma unroll
    for (int cb = 0; cb < 2; ++cb) {
      const int nl = wn * 32 + cb * 16 + l16;       // 0..63
      const int n = n0 + nl;
      const int h = n >> 7;
      const float bz = b_z[n], ba = b_za[n];
      float ssum = 0.f;
#pragma unroll
      for (int rb = 0; rb < 4; ++rb) {
        const int mlb = wm * 64 + rb * 16 + quad * 4;
#pragma unroll
        for (int r = 0; r < 4; ++r) {
          const int l = (m0 + mlb + r) & (L_SEQ - 1);
          float u  = acc[rb][cb][r] + bz;
          float vv = acc[rb][cb + 2][r] + ba;
          if (l > h) ssum += u * silu_f(vv);
          else if (l == h)
            wdiag[(size_t)(b * NH + h) * 128 + (n & 127)] = u * silu_f(vv);
        }
      }
      atomicAdd(&colsum[nl], ssum);
    }
    __syncthreads();
    if (tid < 64) atomicAdd(&Zs[(size_t)b * DIM + n0 + tid], colsum[tid]);
  } else {
#pragma unroll
    for (int cb = 0; cb < 4; ++cb) {
      const int nl = wn * 64 + cb * 16 + l16;       // 0..127
      const float bb = b_ya[n0 + nl];
#pragma unroll
      for (int rb = 0; rb < 4; ++rb) {
        const int mlb = wm * 64 + rb * 16 + quad * 4;
#pragma unroll
        for (int r = 0; r < 4; ++r)
          Sy[(size_t)(m0 + mlb + r) * DIM + n0 + nl] = silu_f(acc[rb][cb][r] + bb);
      }
    }
  }
}

// ---- per (b,h): stats on wave 0, then 4-wave parallel scan (8 chunks/wave) ----
__global__ __launch_bounds__(256) void stats_scan(const float* __restrict__ Zs,
                                                  const float* __restrict__ hidden,
                                                  const float* __restrict__ wdiag,
                                                  const float* __restrict__ gn_w,
                                                  const float* __restrict__ ln_da,
                                                  float* __restrict__ vtg,
                                                  float* __restrict__ wtg,
                                                  float* __restrict__ alpha2,
                                                  float* __restrict__ hidden_next) {
  const int bh = blockIdx.x, b = bh >> 3, h = bh & 7;
  const int tid = threadIdx.x, wv = tid >> 6, lane = tid & 63;
  __shared__ float csumS[32];
  __shared__ float statS[4];   // svv, svw, sww, total

  float v0 = 0.f, v1 = 0.f, w0 = 0.f, w1 = 0.f;
  const size_t base = (size_t)bh * 128;
  if (wv == 0) {
    v0 = Zs[(size_t)b * DIM + h * 128 + lane]      + hidden[base + lane];
    v1 = Zs[(size_t)b * DIM + h * 128 + 64 + lane] + hidden[base + 64 + lane];
    w0 = wdiag[base + lane];
    w1 = wdiag[base + 64 + lane];
    float sv = v0 + v1, sw = w0 + w1;
    for (int off = 32; off > 0; off >>= 1) {
      sv += __shfl_down(sv, off);
      sw += __shfl_down(sw, off);
    }
    const float muv = __shfl(sv, 0) * (1.f / 128.f);
    const float muw = __shfl(sw, 0) * (1.f / 128.f);
    const float a0 = v0 - muv, a1 = v1 - muv;
    const float c0 = w0 - muw, c1 = w1 - muw;
    float rvv = a0 * a0 + a1 * a1;
    float rvw = a0 * c0 + a1 * c1;
    float rww = c0 * c0 + c1 * c1;
    for (int off = 32; off > 0; off >>= 1) {
      rvv += __shfl_down(rvv, off);
      rvw += __shfl_down(rvw, off);
      rww += __shfl_down(rww, off);
    }
    if (lane == 0) {
      statS[0] = rvv * (1.f / 128.f);
      statS[1] = rvw * (1.f / 128.f);
      statS[2] = rww * (1.f / 128.f);
    }
    const float gw = gn_w[h];
    vtg[base + lane] = a0 * gw;  vtg[base + 64 + lane] = a1 * gw;
    wtg[base + lane] = c0 * gw;  wtg[base + 64 + lane] = c1 * gw;
  }

  // phase 1: per-wave intra-chunk inclusive prefix on 8 chunks
  const float* src = ln_da + (size_t)bh * L_SEQ;
  float vals[8];
#pragma unroll
  for (int jj = 0; jj < 8; ++jj) {
    const int c = wv * 8 + jj;
    float val = src[c * 64 + lane];
#pragma unroll
    for (int off = 1; off < 64; off <<= 1) {
      float nv = __shfl_up(val, off);
      if (lane >= off) val += nv;
    }
    vals[jj] = val;
    if (lane == 63) csumS[c] = val;
  }
  __syncthreads();

  // phase 2: wave 0 lanes 0..31: exclusive scan of the 32 chunk totals
  if (tid < 32) {
    float s = csumS[tid];
    float incl = s;
#pragma unroll
    for (int off = 1; off < 32; off <<= 1) {
      float nv = __shfl_up(incl, off);
      if (tid >= off) incl += nv;
    }
    csumS[tid] = incl - s;            // exclusive carry
    if (tid == 31) statS[3] = incl;   // grand total
  }
  __syncthreads();

  // phase 3: apply carries, compute alpha2
  const float svv = statS[0], svw = statS[1], sww = statS[2];
#pragma unroll
  for (int jj = 0; jj < 8; ++jj) {
    const int c = wv * 8 + jj;
    const float S = csumS[c] + vals[jj];
    const float ce = expf(S);
    const float D = rsqrtf(ce * ce * svv + 2.f * ce * svw + sww + EPS_F);
    const int l = c * 64 + lane;
    float* ap = alpha2 + ((size_t)(b * L_SEQ + l) * NH + h) * 2;
    ap[0] = ce * D;
    ap[1] = D;
  }
  if (wv == 0) {
    const float clast = expf(statS[3]);
    hidden_next[base + lane]      = clast * v0 + w0;
    hidden_next[base + 64 + lane] = clast * v1 + w1;
  }
}

// ---- per row n of W_y: Gv[bh][n], Gw[bh][n] (all 16 bh) and constc[n] ----
__global__ __launch_bounds__(256) void proj_kernel(const float* __restrict__ W_y,
                                                   const float* __restrict__ vtg,
                                                   const float* __restrict__ wtg,
                                                   const float* __restrict__ gn_b,
                                                   const float* __restrict__ b_y,
                                                   float* __restrict__ Gv,
                                                   float* __restrict__ Gw,
                                                   float* __restrict__ constc) {
  const int tid = threadIdx.x, wave = tid >> 6, lane = tid & 63;
  const int n = blockIdx.x * 4 + wave;
  const float4* row = (const float4*)(W_y + (size_t)n * DIM);
  const int half = lane >> 5, l32 = lane & 31;
  float cc = 0.f;
#pragma unroll
  for (int p = 0; p < 4; ++p) {
    const int h = p * 2 + half;
    float4 wv = row[p * 64 + lane];
    const float4 va = *(const float4*)&vtg[(size_t)h * 128 + l32 * 4];
    const float4 vb = *(const float4*)&vtg[(size_t)(8 + h) * 128 + l32 * 4];
    const float4 wa = *(const float4*)&wtg[(size_t)h * 128 + l32 * 4];
    const float4 wb = *(const float4*)&wtg[(size_t)(8 + h) * 128 + l32 * 4];
    float gv0 = wv.x * va.x + wv.y * va.y + wv.z * va.z + wv.w * va.w;
    float gv1 = wv.x * vb.x + wv.y * vb.y + wv.z * vb.z + wv.w * vb.w;
    float gw0 = wv.x * wa.x + wv.y * wa.y + wv.z * wa.z + wv.w * wa.w;
    float gw1 = wv.x * wb.x + wv.y * wb.y + wv.z * wb.z + wv.w * wb.w;
    cc += (wv.x + wv.y + wv.z + wv.w) * gn_b[h];
#pragma unroll
    for (int off = 16; off > 0; off >>= 1) {
      gv0 += __shfl_down(gv0, off, 32);
      gv1 += __shfl_down(gv1, off, 32);
      gw0 += __shfl_down(gw0, off, 32);
      gw1 += __shfl_down(gw1, off, 32);
    }
    if (l32 == 0) {
      Gv[(size_t)h * DIM + n]       = gv0;
      Gv[(size_t)(8 + h) * DIM + n] = gv1;
      Gw[(size_t)h * DIM + n]       = gw0;
      Gw[(size_t)(8 + h) * DIM + n] = gw1;
    }
  }
  for (int off = 32; off > 0; off >>= 1) cc += __shfl_down(cc, off);
  if (lane == 0) constc[n] = b_y[n] + cc;
}

// ---- finalize: y[m,n] = (constc[n] + sum_k alpha2[m,k]*G[k,n]) * Sy[m,n], in place ----
__global__ __launch_bounds__(256) void finalize(const float* __restrict__ alpha2,
                                                const float* __restrict__ Gv,
                                                const float* __restrict__ Gw,
                                                const float* __restrict__ constc,
                                                float* __restrict__ y) {
  const int tid = threadIdx.x;
  const int n0 = blockIdx.x * 256;
  const int m0 = blockIdx.y * 64;
  const int b = m0 >> 11;
  __shared__ float aS[64 * 16];
  ((float4*)aS)[tid] = ((const float4*)(alpha2 + (size_t)m0 * 16))[tid];
  __syncthreads();
  const int c = tid & 63;     // col4 within n-tile
  const int rg = tid >> 6;    // row group (16 rows each)
  const int n = n0 + c * 4;
  f32x4 g[16 * 2];
#pragma unroll
  for (int h = 0; h < 8; ++h) {
    g[2 * h]     = *(const f32x4*)&Gv[(size_t)(b * NH + h) * DIM + n];
    g[2 * h + 1] = *(const f32x4*)&Gw[(size_t)(b * NH + h) * DIM + n];
  }
  const f32x4 cc = *(const f32x4*)&constc[n];
#pragma unroll
  for (int jj = 0; jj < 16; ++jj) {
    const int m = m0 + rg * 16 + jj;
    const float* a = &aS[(rg * 16 + jj) * 16];
    f32x4 Ay = cc;
#pragma unroll
    for (int k = 0; k < 16; ++k) Ay += a[k] * g[k];
    f32x4 s = *(const f32x4*)&y[(size_t)m * DIM + n];
    *(f32x4*)&y[(size_t)m * DIM + n] = Ay * s;
  }
}

extern "C" void kernel_launch(void* const* d_in, const int* in_sizes, int n_in,
                              void* d_out, int out_size, void* d_ws, size_t ws_size,
                              hipStream_t stream) {
  const float* x      = (const float*)d_in[0];
  const float* hidden = (const float*)d_in[1];
  const float* W_z    = (const float*)d_in[2];
  const float* b_z    = (const float*)d_in[3];
  const float* W_za   = (const float*)d_in[4];
  const float* b_za   = (const float*)d_in[5];
  const float* W_y    = (const float*)d_in[6];
  const float* b_y    = (const float*)d_in[7];
  const float* W_ya   = (const float*)d_in[8];
  const float* b_ya   = (const float*)d_in[9];
  const float* W_dt   = (const float*)d_in[10];
  const float* b_dt   = (const float*)d_in[11];
  const float* ln_a   = (const float*)d_in[12];
  const float* gn_w   = (const float*)d_in[13];
  const float* gn_b   = (const float*)d_in[14];

  char* ws = (char*)d_ws;
  unsigned short* xb   = (unsigned short*)(ws);             // 8,388,608 B
  unsigned short* Wzb  = (unsigned short*)(ws + 8388608);   // 2,097,152 B
  unsigned short* Wzab = (unsigned short*)(ws + 10485760);  // 2,097,152 B
  unsigned short* Wyab = (unsigned short*)(ws + 12582912);  // 2,097,152 B
  float* ln_da  = (float*)(ws + 14680064);                  // 131,072 B
  float* Zs     = (float*)(ws + 14811136);                  // 8,192 B
  float* wdiag  = (float*)(ws + 14819328);                  // 8,192 B
  float* vtg    = (float*)(ws + 14827520);                  // 8,192 B
  float* wtg    = (float*)(ws + 14835712);                  // 8,192 B
  float* Gv     = (float*)(ws + 14843904);                  // 65,536 B
  float* Gw     = (float*)(ws + 14909440);                  // 65,536 B
  float* constc = (float*)(ws + 14974976);                  // 4,096 B
  float* alpha2 = (float*)(ws + 14979072);                  // 262,144 B

  float* y = (float*)d_out;
  float* hidden_next = y + (size_t)M_TOT * DIM;

  prep_kernel<<<7168, 256, 0, stream>>>(x, W_dt, b_dt, ln_a,
                                        (const float4*)W_z, (const float4*)W_za,
                                        (const float4*)W_ya,
                                        ln_da, xb, (ushort4*)Wzb, (ushort4*)Wzab,
                                        (ushort4*)Wyab, Zs);

  gemm_all<<<768, 256, 0, stream>>>(xb, Wzb, Wzab, Wyab,
                                    b_z, b_za, b_ya, Zs, wdiag, y);

  stats_scan<<<16, 256, 0, stream>>>(Zs, hidden, wdiag, gn_w, ln_da,
                                     vtg, wtg, alpha2, hidden_next);
  proj_kernel<<<256, 256, 0, stream>>>(W_y, vtg, wtg, gn_b, b_y, Gv, Gw, constc);

  finalize<<<dim3(4, 64), 256, 0, stream>>>(alpha2, Gv, Gw, constc, y);
}